// Round 27
// baseline (410.053 us; speedup 1.0000x reference)
//
#include <hip/hip_runtime.h>
#include <stdint.h>

#define N_NODES 32768
#define NPER    8192
#define NB      4
#define KK      20
#define DH      128

typedef unsigned long long u64;
typedef unsigned short ushort;

__device__ __forceinline__ ushort f2bf(float f) {      // RNE float->bf16
  unsigned x = __float_as_uint(f);
  return (ushort)((x + 0x7fff + ((x >> 16) & 1)) >> 16);
}
__device__ __forceinline__ float bflo(unsigned u) { return __uint_as_float(u << 16); }
__device__ __forceinline__ float bfhi(unsigned u) { return __uint_as_float(u & 0xffff0000u); }

__device__ __forceinline__ u64 shflx64(u64 x, int m) {
  unsigned lo = __shfl_xor((unsigned)(x & 0xffffffffu), m, 64);
  unsigned hi = __shfl_xor((unsigned)(x >> 32), m, 64);
  return (((u64)hi) << 32) | lo;
}
__device__ __forceinline__ u64 shfl64(u64 x, int src) {
  unsigned lo = __shfl((unsigned)(x & 0xffffffffu), src, 64);
  unsigned hi = __shfl((unsigned)(x >> 32), src, 64);
  return (((u64)hi) << 32) | lo;
}
__device__ __forceinline__ int mbcnt64(u64 mask) {
  return __builtin_amdgcn_mbcnt_hi((unsigned)(mask >> 32),
         __builtin_amdgcn_mbcnt_lo((unsigned)mask, 0u));
}
// 64-lane bitonic sort, ascending across lanes (u64 keys)
__device__ __forceinline__ u64 bsort64(u64 key, int lane) {
#pragma unroll
  for (int k = 2; k <= 64; k <<= 1) {
#pragma unroll
    for (int j = k >> 1; j >= 1; j >>= 1) {
      u64 other = shflx64(key, j);
      bool up = ((lane & k) == 0);
      bool keepmin = (((lane & j) == 0) == up);
      bool take = keepmin ? (other < key) : (other > key);
      key = take ? other : key;
    }
  }
  return key;
}
// 64-lane bitonic sort, ascending, u32 keys (half the shuffle cost)
__device__ __forceinline__ unsigned bsortu32(unsigned key, int lane) {
#pragma unroll
  for (int k = 2; k <= 64; k <<= 1) {
#pragma unroll
    for (int j = k >> 1; j >= 1; j >>= 1) {
      unsigned other = (unsigned)__shfl_xor((int)key, j, 64);
      bool up = ((lane & k) == 0);
      bool keepmin = (((lane & j) == 0) == up);
      bool take = keepmin ? (other < key) : (other > key);
      key = take ? other : key;
    }
  }
  return key;
}
// bitonic merge-clean (input bitonic, output ascending)
__device__ __forceinline__ u64 bclean64(u64 key, int lane) {
#pragma unroll
  for (int j = 32; j >= 1; j >>= 1) {
    u64 other = shflx64(key, j);
    bool keepmin = ((lane & j) == 0);
    bool take = keepmin ? (other < key) : (other > key);
    key = take ? other : key;
  }
  return key;
}

// Fold <=64 NEW buffered keys into register-kept sorted list lo (21 valid + pad):
// one bsort64 of the new keys, half-cleaner merge vs lo, bclean. Tighten thr.
__device__ __forceinline__ void compact64(u64* bufr, int& cnt, u64& lo,
                                          unsigned& thr, int lane) {
  asm volatile("s_waitcnt lgkmcnt(0)" ::: "memory");
  u64 k = (lane < cnt) ? bufr[lane] : ~0ull;
  k = bsort64(k, lane);                     // new keys ascending
  u64 kr = shfl64(k, 63 - lane);            // descending copy
  u64 m = (kr < lo) ? kr : lo;              // half-cleaner: 64 smallest of 128, bitonic
  lo = bclean64(m, lane);                   // sorted ascending
  thr = (unsigned)(shfl64(lo, KK) >> 32);   // d2-bits of 21st smallest (incl self)
  cnt = 0;
  asm volatile("s_waitcnt lgkmcnt(0)" ::: "memory");
}

// One wave per TWO consecutive rows; lane handles FOUR consecutive candidates per
// iteration. Threshold primed from lane-mins over SIXTEEN candidates (iters 0-3):
// 21st-of-min-of-16 is a valid upper bound on the true 21st (21 smallest lane-mins
// map to 21 distinct candidates) at a ~2x tighter quantile than min-of-8.
// Per-r ballot gating skips bookkeeping for survivor-free batches. Sorted top-21
// in regs; LDS holds only new appends; self stripped at output.
// Exact top-20 by (d2, idx).
__global__ __launch_bounds__(256) void knn_kernel(const float* __restrict__ pos,
                                                  int* __restrict__ knn)
{
  __shared__ u64 buf[8][64];

  const int lane = threadIdx.x & 63;
  const int w    = threadIdx.x >> 6;
  const int rowA = blockIdx.x * 8 + w * 2;
  const int rowB = rowA + 1;
  const int base = (rowA >> 13) << 13;   // graph start

  const float ax = pos[rowA*3+0], ay = pos[rowA*3+1], az = pos[rowA*3+2];
  const float bx = pos[rowB*3+0], by = pos[rowB*3+1], bz = pos[rowB*3+2];

  unsigned thra, thrb;
  int cnta = 0, cntb = 0;
  u64 loa = ~0ull, lob = ~0ull;
  u64* bufa = buf[w*2+0];
  u64* bufb = buf[w*2+1];

  const float4* __restrict__ p4 = (const float4*)(pos + (size_t)base*3);

  // ---- prime thresholds from iterations 0-3 (lane-min-of-16 upper bound) ----
  {
    float mA = 3.4e38f, mB = 3.4e38f;
#pragma unroll
    for (int pit = 0; pit < 4; pit++) {
      const int f4 = pit*192 + lane*3;
      float4 q0 = p4[f4+0];
      float4 q1 = p4[f4+1];
      float4 q2 = p4[f4+2];
      const float X[4] = {q0.x, q0.w, q1.z, q2.y};
      const float Y[4] = {q0.y, q1.x, q1.w, q2.z};
      const float Z[4] = {q0.z, q1.y, q2.x, q2.w};
#pragma unroll
      for (int r = 0; r < 4; r++) {
        float dx = ax - X[r], dy = ay - Y[r], dz = az - Z[r];
        mA = fminf(mA, fmaf(dx, dx, fmaf(dy, dy, dz*dz)));
        float ex = bx - X[r], ey = by - Y[r], ez = bz - Z[r];
        mB = fminf(mB, fmaf(ex, ex, fmaf(ey, ey, ez*ez)));
      }
    }
    unsigned sA = bsortu32(__float_as_uint(mA), lane);
    unsigned sB = bsortu32(__float_as_uint(mB), lane);
    thra = (unsigned)__shfl((int)sA, KK, 64);   // 21st smallest lane-min
    thrb = (unsigned)__shfl((int)sB, KK, 64);
  }

  for (int it = 0; it < 32; it++) {
    const int c0 = it*256 + lane*4;            // 4 consecutive candidates
    const int f4 = it*192 + lane*3;            // float4 index of candidate block
    float4 q0 = p4[f4+0];
    float4 q1 = p4[f4+1];
    float4 q2 = p4[f4+2];
    const float X[4] = {q0.x, q0.w, q1.z, q2.y};
    const float Y[4] = {q0.y, q1.x, q1.w, q2.z};
    const float Z[4] = {q0.z, q1.y, q2.x, q2.w};

    float dA[4], dB[4];
#pragma unroll
    for (int r = 0; r < 4; r++) {
      float dx = ax - X[r], dy = ay - Y[r], dz = az - Z[r];
      dA[r] = fmaf(dx, dx, fmaf(dy, dy, dz*dz));
      float ex = bx - X[r], ey = by - Y[r], ez = bz - Z[r];
      dB[r] = fmaf(ex, ex, fmaf(ey, ey, ez*ez));
    }
    float mnA = fminf(fminf(dA[0], dA[1]), fminf(dA[2], dA[3]));
    float mnB = fminf(fminf(dB[0], dB[1]), fminf(dB[2], dB[3]));

    if (__any(__float_as_uint(mnA) <= thra)) {
#pragma unroll
      for (int r = 0; r < 4; r++) {
        unsigned bits = __float_as_uint(dA[r]);
        bool pred = (bits <= thra);
        u64 mask = __ballot(pred);
        if (mask) {
          int pc = __popcll(mask);
          if (cnta + pc > 64) compact64(bufa, cnta, loa, thra, lane);
          if (pred) bufa[cnta + mbcnt64(mask)] =
              (((u64)bits) << 32) | (unsigned)(base + c0 + r);
          cnta = __builtin_amdgcn_readfirstlane(cnta + pc);
        }
      }
    }
    if (__any(__float_as_uint(mnB) <= thrb)) {
#pragma unroll
      for (int r = 0; r < 4; r++) {
        unsigned bits = __float_as_uint(dB[r]);
        bool pred = (bits <= thrb);
        u64 mask = __ballot(pred);
        if (mask) {
          int pc = __popcll(mask);
          if (cntb + pc > 64) compact64(bufb, cntb, lob, thrb, lane);
          if (pred) bufb[cntb + mbcnt64(mask)] =
              (((u64)bits) << 32) | (unsigned)(base + c0 + r);
          cntb = __builtin_amdgcn_readfirstlane(cntb + pc);
        }
      }
    }
  }
  compact64(bufa, cnta, loa, thra, lane);
  compact64(bufb, cntb, lob, thrb, lane);

  // strip self (d2=0 guarantees membership in the 21); output order irrelevant
  {
    u64 ball = __ballot(((int)(loa & 0xffffffffu) == rowA) && (lane <= KK));
    int p0 = __ffsll((long long)ball) - 1;
    if (p0 < 0) p0 = KK + 1;
    int src = lane + ((lane >= p0) ? 1 : 0);
    u64 outk = shfl64(loa, src);
    if (lane < KK) knn[rowA*KK + lane] = (int)(outk & 0xffffffffu);
  }
  {
    u64 ball = __ballot(((int)(lob & 0xffffffffu) == rowB) && (lane <= KK));
    int p0 = __ffsll((long long)ball) - 1;
    if (p0 < 0) p0 = KK + 1;
    int src = lane + ((lane >= p0) ? 1 : 0);
    u64 outk = shfl64(lob, src);
    if (lane < KK) knn[rowB*KK + lane] = (int)(outk & 0xffffffffu);
  }
}

// pos4[i] = (x,y,z,0): 16B-aligned position table so gathers are ONE float4 load.
__global__ void pos4_kernel(const float* __restrict__ pos, float4* __restrict__ pos4)
{
  int i = blockIdx.x * 256 + threadIdx.x;
  if (i >= N_NODES) return;
  pos4[i] = make_float4(pos[i*3+0], pos[i*3+1], pos[i*3+2], 0.f);
}

// forward edge e=(i -> d=knn[i][j]); mutual iff i in knn(d). Non-mutual edges need a CSR slot.
__global__ void count_kernel(const int* __restrict__ knn, int* __restrict__ flags,
                             int* __restrict__ cnt)
{
  int e = blockIdx.x * 256 + threadIdx.x;
  if (e >= N_NODES*KK) return;
  int i = e / KK;
  int d = knn[e];
  int mut = 0;
#pragma unroll
  for (int t = 0; t < KK; t++) mut |= (knn[d*KK + t] == i);
  flags[e] = mut;
  if (!mut) atomicAdd(&cnt[d], 1);
}

__global__ __launch_bounds__(1024) void scan_kernel(const int* __restrict__ cnt,
                                                    int* __restrict__ off)
{
  __shared__ int ssum[1024];
  int tid = threadIdx.x;
  int i0 = tid * 32;
  int loc[32];
  int s = 0;
#pragma unroll
  for (int j = 0; j < 32; j++) { loc[j] = s; s += cnt[i0 + j]; }
  ssum[tid] = s;
  __syncthreads();
  for (int d = 1; d < 1024; d <<= 1) {
    int t = (tid >= d) ? ssum[tid - d] : 0;
    __syncthreads();
    ssum[tid] += t;
    __syncthreads();
  }
  int bse = ssum[tid] - s;             // exclusive base
#pragma unroll
  for (int j = 0; j < 32; j++) off[i0 + j] = bse + loc[j];
  if (tid == 1023) off[N_NODES] = bse + s;
}

__global__ void fill_kernel(const int* __restrict__ knn, const int* __restrict__ flags,
                            const int* __restrict__ off, int* __restrict__ cursor,
                            int* __restrict__ extra)
{
  int e = blockIdx.x * 256 + threadIdx.x;
  if (e >= N_NODES*KK) return;
  if (flags[e]) return;
  int i = e / KK;
  int d = knn[e];
  int p = atomicAdd(&cursor[d], 1);
  extra[off[d] + p] = i;
}

// Y = X @ W (+ bias [*deg]) [+relu]; X:[n,128] f32, W:[128,128] row-major.
// OBF16: store Y as bf16 (RNE). Full W staged in LDS; ONE barrier.
// XCD-graph swizzle kept (neutral, harmless): p%8 in {2g,2g+1}.
template<int RELU, int DEG, int OBF16>
__global__ __launch_bounds__(256) void gemm128(const float* __restrict__ X,
    const float* __restrict__ W, const float* __restrict__ bias,
    const int* __restrict__ offs, void* __restrict__ Yv)
{
  __shared__ float ws[128*128];
  const int tid = threadIdx.x;
  const int p   = blockIdx.x;             // 512 blocks
  const int g   = (p & 7) >> 1;
  const int j   = ((p >> 3) << 1) | (p & 1);
  const int r0  = g*NPER + j*64;

  {
    const float4* W4 = (const float4*)W;
    float4* ws4 = (float4*)ws;
#pragma unroll
    for (int li = 0; li < 16; li++) ws4[tid + li*256] = W4[tid + li*256];
  }
  __syncthreads();

  const int tr = tid >> 4, tc = tid & 15;
  const int rr0 = tr*4, cc0 = tc*8;
  float acc[4][8];
#pragma unroll
  for (int a = 0; a < 4; a++)
#pragma unroll
    for (int c = 0; c < 8; c++) acc[a][c] = 0.f;

  for (int kc = 0; kc < 32; kc++) {
    float4 xr[4];
#pragma unroll
    for (int rr = 0; rr < 4; rr++)
      xr[rr] = *(const float4*)&X[(size_t)(r0 + rr0 + rr)*128 + kc*4];
#pragma unroll
    for (int kk = 0; kk < 4; kk++) {
      float4 wA = *(const float4*)&ws[(kc*4 + kk)*128 + cc0];
      float4 wB = *(const float4*)&ws[(kc*4 + kk)*128 + cc0 + 4];
      float wv[8] = {wA.x, wA.y, wA.z, wA.w, wB.x, wB.y, wB.z, wB.w};
      float xa[4] = {kk==0?xr[0].x:kk==1?xr[0].y:kk==2?xr[0].z:xr[0].w,
                     kk==0?xr[1].x:kk==1?xr[1].y:kk==2?xr[1].z:xr[1].w,
                     kk==0?xr[2].x:kk==1?xr[2].y:kk==2?xr[2].z:xr[2].w,
                     kk==0?xr[3].x:kk==1?xr[3].y:kk==2?xr[3].z:xr[3].w};
#pragma unroll
      for (int rr = 0; rr < 4; rr++)
#pragma unroll
        for (int cc = 0; cc < 8; cc++) acc[rr][cc] += xa[rr] * wv[cc];
    }
  }
#pragma unroll
  for (int rr = 0; rr < 4; rr++) {
    int r = r0 + rr0 + rr;
    float dg = 1.f;
    if (DEG) dg = (float)(KK + offs[r+1] - offs[r]);
    float o[8];
#pragma unroll
    for (int cc = 0; cc < 8; cc++) {
      float vv = acc[rr][cc] + bias[cc0+cc] * dg;
      if (RELU) vv = fmaxf(vv, 0.f);
      o[cc] = vv;
    }
    if (OBF16) {
      ushort* Y = (ushort*)Yv;
      unsigned pk[4];
#pragma unroll
      for (int q = 0; q < 4; q++)
        pk[q] = (unsigned)f2bf(o[2*q]) | ((unsigned)f2bf(o[2*q+1]) << 16);
      *(uint4*)&Y[(size_t)r*128 + cc0] = make_uint4(pk[0], pk[1], pk[2], pk[3]);
    } else {
      float* Y = (float*)Yv;
      *(float4*)&Y[(size_t)r*128 + cc0]     = make_float4(o[0], o[1], o[2], o[3]);
      *(float4*)&Y[(size_t)r*128 + cc0 + 4] = make_float4(o[4], o[5], o[6], o[7]);
    }
  }
}

// agg[d] = sum over in-neighbors s of relu(H[s] + (pos[d]-pos[s]) @ Wr).
// H bf16 [N,128] (256B rows): FOUR nodes per wave (16 lanes each, 8 cols/lane).
// MLP batching: issue 4 neighbors' pos4+H loads (8 independent VMEM) before any
// compute, statically unrolled (5 batches of 4) -- explicit memory-level
// parallelism in case hipcc wasn't software-pipelining the interleaved chain.
__global__ __launch_bounds__(256) void agg_kernel(const ushort* __restrict__ H,
    const float4* __restrict__ pos4, const int* __restrict__ knn,
    const int* __restrict__ off, const int* __restrict__ extra,
    const float* __restrict__ Wr, float* __restrict__ agg)
{
  const int lane = threadIdx.x & 63;
  const int w    = threadIdx.x >> 6;
  const int grp  = lane >> 4;             // node within wave
  const int hl   = lane & 15;             // lane within node group
  const int dblk = blockIdx.x;            // 2048 blocks
  const int g    = (dblk >> 1) & 3;
  const int nb   = ((dblk >> 3) << 1) | (dblk & 1);   // 0..511
  const int d    = g*NPER + nb*16 + w*4 + grp;
  const int c0   = hl * 8;

  // preload all 20 neighbor indices (80B contiguous)
  const int4* kn4 = (const int4*)&knn[d*KK];
  int4 i0 = kn4[0], i1 = kn4[1], i2 = kn4[2], i3 = kn4[3], i4 = kn4[4];
  const int e0 = off[d], e1 = off[d+1];
  const int idx[KK] = {i0.x,i0.y,i0.z,i0.w, i1.x,i1.y,i1.z,i1.w,
                       i2.x,i2.y,i2.z,i2.w, i3.x,i3.y,i3.z,i3.w,
                       i4.x,i4.y,i4.z,i4.w};

  // 8 columns of Wr per lane
  float w0[8], w1[8], w2[8];
#pragma unroll
  for (int jj = 0; jj < 8; jj++) {
    w0[jj] = Wr[0*DH + c0 + jj];
    w1[jj] = Wr[1*DH + c0 + jj];
    w2[jj] = Wr[2*DH + c0 + jj];
  }
  const float4 pd = pos4[d];
  const float px = pd.x, py = pd.y, pz = pd.z;

  float a[8];
#pragma unroll
  for (int jj = 0; jj < 8; jj++) a[jj] = 0.f;

#pragma unroll
  for (int tb = 0; tb < 5; tb++) {
    const int s0 = idx[tb*4+0], s1 = idx[tb*4+1], s2 = idx[tb*4+2], s3 = idx[tb*4+3];
    // issue all 8 loads first (static names -> registers, no scratch)
    float4 ps0 = pos4[s0], ps1 = pos4[s1], ps2 = pos4[s2], ps3 = pos4[s3];
    uint4 hv0 = *(const uint4*)&H[(size_t)s0*DH + c0];
    uint4 hv1 = *(const uint4*)&H[(size_t)s1*DH + c0];
    uint4 hv2 = *(const uint4*)&H[(size_t)s2*DH + c0];
    uint4 hv3 = *(const uint4*)&H[(size_t)s3*DH + c0];
#pragma unroll
    for (int q = 0; q < 4; q++) {
      float4 ps = (q==0) ? ps0 : (q==1) ? ps1 : (q==2) ? ps2 : ps3;
      uint4 hv  = (q==0) ? hv0 : (q==1) ? hv1 : (q==2) ? hv2 : hv3;
      float rx = px - ps.x, ry = py - ps.y, rz = pz - ps.z;
      float h[8] = {bflo(hv.x), bfhi(hv.x), bflo(hv.y), bfhi(hv.y),
                    bflo(hv.z), bfhi(hv.z), bflo(hv.w), bfhi(hv.w)};
#pragma unroll
      for (int jj = 0; jj < 8; jj++) {
        float m = h[jj] + rx*w0[jj] + ry*w1[jj] + rz*w2[jj];
        a[jj] += fmaxf(m, 0.f);
      }
    }
  }
  for (int t = e0; t < e1; t++) {
    int s = extra[t];
    float4 ps = pos4[s];
    float rx = px - ps.x, ry = py - ps.y, rz = pz - ps.z;
    uint4 hv = *(const uint4*)&H[(size_t)s*DH + c0];
    float h[8] = {bflo(hv.x), bfhi(hv.x), bflo(hv.y), bfhi(hv.y),
                  bflo(hv.z), bfhi(hv.z), bflo(hv.w), bfhi(hv.w)};
#pragma unroll
    for (int jj = 0; jj < 8; jj++) {
      float m = h[jj] + rx*w0[jj] + ry*w1[jj] + rz*w2[jj];
      a[jj] += fmaxf(m, 0.f);
    }
  }
  *(float4*)&agg[(size_t)d*DH + c0]     = make_float4(a[0], a[1], a[2], a[3]);
  *(float4*)&agg[(size_t)d*DH + c0 + 4] = make_float4(a[4], a[5], a[6], a[7]);
}

// logits[n] = dot(X[n], Wf) + bf — WIDE (128 blocks, coalesced streaming).
__global__ __launch_bounds__(256) void logits_kernel(const float* __restrict__ X,
    const float* __restrict__ Wf, const float* __restrict__ bf,
    float* __restrict__ logits)
{
  const int n = blockIdx.x * 256 + threadIdx.x;
  const float4* xr = (const float4*)&X[(size_t)n*128];
  float acc = 0.f;
#pragma unroll 8
  for (int q = 0; q < 32; q++) {
    float4 xv = xr[q];
    float4 wv = *(const float4*)&Wf[q*4];
    acc += xv.x*wv.x + xv.y*wv.y + xv.z*wv.z + xv.w*wv.w;
  }
  logits[n] = acc + bf[0];
}

// per-graph softmax over 8192 logits (128 KB total; registers + 2 block reduces).
__global__ __launch_bounds__(1024) void softmax_kernel(const float* __restrict__ logits,
    float* __restrict__ out)
{
  __shared__ float red[16];
  __shared__ float bcast;
  const int g = blockIdx.x, tid = threadIdx.x;
  const int lane = tid & 63, wid = tid >> 6;
  float lg[8];
#pragma unroll
  for (int k = 0; k < 8; k++) lg[k] = logits[g*NPER + k*1024 + tid];
  float m = lg[0];
#pragma unroll
  for (int k = 1; k < 8; k++) m = fmaxf(m, lg[k]);
  for (int o = 1; o < 64; o <<= 1) m = fmaxf(m, __shfl_xor(m, o, 64));
  if (lane == 0) red[wid] = m;
  __syncthreads();
  if (tid == 0) {
    float mm = red[0];
    for (int i = 1; i < 16; i++) mm = fmaxf(mm, red[i]);
    bcast = mm;
  }
  __syncthreads();
  const float M = bcast;
  float e[8];
  float s = 0.f;
#pragma unroll
  for (int k = 0; k < 8; k++) { e[k] = expf(lg[k] - M); s += e[k]; }
  for (int o = 1; o < 64; o <<= 1) s += __shfl_xor(s, o, 64);
  __syncthreads();
  if (lane == 0) red[wid] = s;
  __syncthreads();
  if (tid == 0) {
    float ss = 0.f;
    for (int i = 0; i < 16; i++) ss += red[i];
    bcast = ss;
  }
  __syncthreads();
  const float S = bcast;
#pragma unroll
  for (int k = 0; k < 8; k++) {
    int n = g*NPER + k*1024 + tid;
    out[n] = e[k] / S;
  }
}

extern "C" void kernel_launch(void* const* d_in, const int* in_sizes, int n_in,
                              void* d_out, int out_size, void* d_ws, size_t ws_size,
                              hipStream_t stream)
{
  const float* x   = (const float*)d_in[0];
  const float* pos = (const float*)d_in[1];
  // d_in[2] = batch (unused: sorted, equal-size graphs)
  const float* W1s = (const float*)d_in[3];
  const float* b1s = (const float*)d_in[4];
  const float* W2s = (const float*)d_in[5];
  const float* b2s = (const float*)d_in[6];
  const float* Wf  = (const float*)d_in[7];
  const float* bf  = (const float*)d_in[8];
  float* out = (float*)d_out;

  char* wsb = (char*)d_ws;
  size_t o = 0;
  auto alloc = [&](size_t bytes) { void* p = wsb + o; o += (bytes + 255) & ~255ull; return p; };
  int*    knn    = (int*)   alloc((size_t)N_NODES*KK*4);
  int*    flags  = (int*)   alloc((size_t)N_NODES*KK*4);
  int*    cnt    = (int*)   alloc((size_t)(N_NODES+1)*4);
  int*    off    = (int*)   alloc((size_t)(N_NODES+1)*4);
  int*    cursor = (int*)   alloc((size_t)N_NODES*4);
  int*    extra  = (int*)   alloc((size_t)N_NODES*KK*4);
  ushort* H      = (ushort*)alloc((size_t)N_NODES*DH*2);   // bf16
  float*  agg    = (float*) alloc((size_t)N_NODES*DH*4);
  float*  xbuf   = (float*) alloc((size_t)N_NODES*DH*4);
  float4* pos4   = (float4*)alloc((size_t)N_NODES*16);
  float*  logits = (float*) alloc((size_t)N_NODES*4);
  (void)ws_size; (void)in_sizes; (void)n_in; (void)out_size;

  hipMemsetAsync(cnt,    0, (size_t)(N_NODES+1)*4, stream);
  hipMemsetAsync(cursor, 0, (size_t)N_NODES*4,     stream);

  knn_kernel <<<N_NODES/8, 256, 0, stream>>>(pos, knn);
  pos4_kernel<<<N_NODES/256, 256, 0, stream>>>(pos, pos4);
  count_kernel<<<(N_NODES*KK + 255)/256, 256, 0, stream>>>(knn, flags, cnt);
  scan_kernel<<<1, 1024, 0, stream>>>(cnt, off);
  fill_kernel<<<(N_NODES*KK + 255)/256, 256, 0, stream>>>(knn, flags, off, cursor, extra);

  const float* xin = x;
  for (int l = 0; l < 3; l++) {
    const float* W1 = W1s + (size_t)l*131*128;   // rows 0..127: x-part
    const float* Wr = W1 + 128*128;              // rows 128..130: rel-part
    const float* b1 = b1s + l*128;
    const float* W2 = W2s + (size_t)l*128*128;
    const float* b2 = b2s + l*128;
    gemm128<0,0,1><<<N_NODES/64, 256, 0, stream>>>(xin, W1, b1, nullptr, H);
    agg_kernel  <<<N_NODES/16, 256, 0, stream>>>(H, pos4, knn, off, extra, Wr, agg);
    gemm128<1,1,0><<<N_NODES/64, 256, 0, stream>>>(agg, W2, b2, off, xbuf);
    xin = xbuf;
  }
  logits_kernel <<<N_NODES/256, 256, 0, stream>>>(xbuf, Wf, bf, logits);
  softmax_kernel<<<NB, 1024, 0, stream>>>(logits, out);
}

// Round 28
// 401.155 us; speedup vs baseline: 1.0222x; 1.0222x over previous
//
#include <hip/hip_runtime.h>
#include <stdint.h>

#define N_NODES 32768
#define NPER    8192
#define NB      4
#define KK      20
#define DH      128

typedef unsigned long long u64;
typedef unsigned short ushort;

__device__ __forceinline__ ushort f2bf(float f) {      // RNE float->bf16
  unsigned x = __float_as_uint(f);
  return (ushort)((x + 0x7fff + ((x >> 16) & 1)) >> 16);
}
__device__ __forceinline__ float bflo(unsigned u) { return __uint_as_float(u << 16); }
__device__ __forceinline__ float bfhi(unsigned u) { return __uint_as_float(u & 0xffff0000u); }

__device__ __forceinline__ u64 shflx64(u64 x, int m) {
  unsigned lo = __shfl_xor((unsigned)(x & 0xffffffffu), m, 64);
  unsigned hi = __shfl_xor((unsigned)(x >> 32), m, 64);
  return (((u64)hi) << 32) | lo;
}
__device__ __forceinline__ u64 shfl64(u64 x, int src) {
  unsigned lo = __shfl((unsigned)(x & 0xffffffffu), src, 64);
  unsigned hi = __shfl((unsigned)(x >> 32), src, 64);
  return (((u64)hi) << 32) | lo;
}
__device__ __forceinline__ int mbcnt64(u64 mask) {
  return __builtin_amdgcn_mbcnt_hi((unsigned)(mask >> 32),
         __builtin_amdgcn_mbcnt_lo((unsigned)mask, 0u));
}
// 64-lane bitonic sort, ascending across lanes (u64 keys)
__device__ __forceinline__ u64 bsort64(u64 key, int lane) {
#pragma unroll
  for (int k = 2; k <= 64; k <<= 1) {
#pragma unroll
    for (int j = k >> 1; j >= 1; j >>= 1) {
      u64 other = shflx64(key, j);
      bool up = ((lane & k) == 0);
      bool keepmin = (((lane & j) == 0) == up);
      bool take = keepmin ? (other < key) : (other > key);
      key = take ? other : key;
    }
  }
  return key;
}
// 64-lane bitonic sort, ascending, u32 keys (half the shuffle cost)
__device__ __forceinline__ unsigned bsortu32(unsigned key, int lane) {
#pragma unroll
  for (int k = 2; k <= 64; k <<= 1) {
#pragma unroll
    for (int j = k >> 1; j >= 1; j >>= 1) {
      unsigned other = (unsigned)__shfl_xor((int)key, j, 64);
      bool up = ((lane & k) == 0);
      bool keepmin = (((lane & j) == 0) == up);
      bool take = keepmin ? (other < key) : (other > key);
      key = take ? other : key;
    }
  }
  return key;
}
// bitonic merge-clean (input bitonic, output ascending)
__device__ __forceinline__ u64 bclean64(u64 key, int lane) {
#pragma unroll
  for (int j = 32; j >= 1; j >>= 1) {
    u64 other = shflx64(key, j);
    bool keepmin = ((lane & j) == 0);
    bool take = keepmin ? (other < key) : (other > key);
    key = take ? other : key;
  }
  return key;
}

// Fold <=64 NEW buffered keys into register-kept sorted list lo (21 valid + pad):
// one bsort64 of the new keys, half-cleaner merge vs lo, bclean. Tighten thr.
__device__ __forceinline__ void compact64(u64* bufr, int& cnt, u64& lo,
                                          unsigned& thr, int lane) {
  asm volatile("s_waitcnt lgkmcnt(0)" ::: "memory");
  u64 k = (lane < cnt) ? bufr[lane] : ~0ull;
  k = bsort64(k, lane);                     // new keys ascending
  u64 kr = shfl64(k, 63 - lane);            // descending copy
  u64 m = (kr < lo) ? kr : lo;              // half-cleaner: 64 smallest of 128, bitonic
  lo = bclean64(m, lane);                   // sorted ascending
  thr = (unsigned)(shfl64(lo, KK) >> 32);   // d2-bits of 21st smallest (incl self)
  cnt = 0;
  asm volatile("s_waitcnt lgkmcnt(0)" ::: "memory");
}

// One wave per TWO consecutive rows; lane handles FOUR consecutive candidates per
// iteration. Threshold primed from lane-mins over EIGHT candidates (iters 0+1) --
// the sweet spot of threshold-tightness vs register pressure (min-of-16 raised
// VGPR 32->40, occupancy 70->53%, and regressed; round-27 evidence). Per-r ballot
// gating skips bookkeeping for survivor-free batches. Sorted top-21 in regs;
// LDS holds only new appends; self stripped at output. Exact top-20 by (d2, idx).
// [Round-26 configuration: measured 134.6us, session optimum.]
__global__ __launch_bounds__(256) void knn_kernel(const float* __restrict__ pos,
                                                  int* __restrict__ knn)
{
  __shared__ u64 buf[8][64];

  const int lane = threadIdx.x & 63;
  const int w    = threadIdx.x >> 6;
  const int rowA = blockIdx.x * 8 + w * 2;
  const int rowB = rowA + 1;
  const int base = (rowA >> 13) << 13;   // graph start

  const float ax = pos[rowA*3+0], ay = pos[rowA*3+1], az = pos[rowA*3+2];
  const float bx = pos[rowB*3+0], by = pos[rowB*3+1], bz = pos[rowB*3+2];

  unsigned thra, thrb;
  int cnta = 0, cntb = 0;
  u64 loa = ~0ull, lob = ~0ull;
  u64* bufa = buf[w*2+0];
  u64* bufb = buf[w*2+1];

  const float4* __restrict__ p4 = (const float4*)(pos + (size_t)base*3);

  // ---- prime thresholds from iterations 0+1 (lane-min-of-8 upper bound) ----
  {
    float mA = 3.4e38f, mB = 3.4e38f;
#pragma unroll
    for (int pit = 0; pit < 2; pit++) {
      const int f4 = pit*192 + lane*3;
      float4 q0 = p4[f4+0];
      float4 q1 = p4[f4+1];
      float4 q2 = p4[f4+2];
      const float X[4] = {q0.x, q0.w, q1.z, q2.y};
      const float Y[4] = {q0.y, q1.x, q1.w, q2.z};
      const float Z[4] = {q0.z, q1.y, q2.x, q2.w};
#pragma unroll
      for (int r = 0; r < 4; r++) {
        float dx = ax - X[r], dy = ay - Y[r], dz = az - Z[r];
        mA = fminf(mA, fmaf(dx, dx, fmaf(dy, dy, dz*dz)));
        float ex = bx - X[r], ey = by - Y[r], ez = bz - Z[r];
        mB = fminf(mB, fmaf(ex, ex, fmaf(ey, ey, ez*ez)));
      }
    }
    unsigned sA = bsortu32(__float_as_uint(mA), lane);
    unsigned sB = bsortu32(__float_as_uint(mB), lane);
    thra = (unsigned)__shfl((int)sA, KK, 64);   // 21st smallest lane-min
    thrb = (unsigned)__shfl((int)sB, KK, 64);
  }

  for (int it = 0; it < 32; it++) {
    const int c0 = it*256 + lane*4;            // 4 consecutive candidates
    const int f4 = it*192 + lane*3;            // float4 index of candidate block
    float4 q0 = p4[f4+0];
    float4 q1 = p4[f4+1];
    float4 q2 = p4[f4+2];
    const float X[4] = {q0.x, q0.w, q1.z, q2.y};
    const float Y[4] = {q0.y, q1.x, q1.w, q2.z};
    const float Z[4] = {q0.z, q1.y, q2.x, q2.w};

    float dA[4], dB[4];
#pragma unroll
    for (int r = 0; r < 4; r++) {
      float dx = ax - X[r], dy = ay - Y[r], dz = az - Z[r];
      dA[r] = fmaf(dx, dx, fmaf(dy, dy, dz*dz));
      float ex = bx - X[r], ey = by - Y[r], ez = bz - Z[r];
      dB[r] = fmaf(ex, ex, fmaf(ey, ey, ez*ez));
    }
    float mnA = fminf(fminf(dA[0], dA[1]), fminf(dA[2], dA[3]));
    float mnB = fminf(fminf(dB[0], dB[1]), fminf(dB[2], dB[3]));

    if (__any(__float_as_uint(mnA) <= thra)) {
#pragma unroll
      for (int r = 0; r < 4; r++) {
        unsigned bits = __float_as_uint(dA[r]);
        bool pred = (bits <= thra);
        u64 mask = __ballot(pred);
        if (mask) {
          int pc = __popcll(mask);
          if (cnta + pc > 64) compact64(bufa, cnta, loa, thra, lane);
          if (pred) bufa[cnta + mbcnt64(mask)] =
              (((u64)bits) << 32) | (unsigned)(base + c0 + r);
          cnta = __builtin_amdgcn_readfirstlane(cnta + pc);
        }
      }
    }
    if (__any(__float_as_uint(mnB) <= thrb)) {
#pragma unroll
      for (int r = 0; r < 4; r++) {
        unsigned bits = __float_as_uint(dB[r]);
        bool pred = (bits <= thrb);
        u64 mask = __ballot(pred);
        if (mask) {
          int pc = __popcll(mask);
          if (cntb + pc > 64) compact64(bufb, cntb, lob, thrb, lane);
          if (pred) bufb[cntb + mbcnt64(mask)] =
              (((u64)bits) << 32) | (unsigned)(base + c0 + r);
          cntb = __builtin_amdgcn_readfirstlane(cntb + pc);
        }
      }
    }
  }
  compact64(bufa, cnta, loa, thra, lane);
  compact64(bufb, cntb, lob, thrb, lane);

  // strip self (d2=0 guarantees membership in the 21); output order irrelevant
  {
    u64 ball = __ballot(((int)(loa & 0xffffffffu) == rowA) && (lane <= KK));
    int p0 = __ffsll((long long)ball) - 1;
    if (p0 < 0) p0 = KK + 1;
    int src = lane + ((lane >= p0) ? 1 : 0);
    u64 outk = shfl64(loa, src);
    if (lane < KK) knn[rowA*KK + lane] = (int)(outk & 0xffffffffu);
  }
  {
    u64 ball = __ballot(((int)(lob & 0xffffffffu) == rowB) && (lane <= KK));
    int p0 = __ffsll((long long)ball) - 1;
    if (p0 < 0) p0 = KK + 1;
    int src = lane + ((lane >= p0) ? 1 : 0);
    u64 outk = shfl64(lob, src);
    if (lane < KK) knn[rowB*KK + lane] = (int)(outk & 0xffffffffu);
  }
}

// pos4[i] = (x,y,z,0): 16B-aligned position table so gathers are ONE float4 load.
__global__ void pos4_kernel(const float* __restrict__ pos, float4* __restrict__ pos4)
{
  int i = blockIdx.x * 256 + threadIdx.x;
  if (i >= N_NODES) return;
  pos4[i] = make_float4(pos[i*3+0], pos[i*3+1], pos[i*3+2], 0.f);
}

// forward edge e=(i -> d=knn[i][j]); mutual iff i in knn(d). Non-mutual edges need a CSR slot.
__global__ void count_kernel(const int* __restrict__ knn, int* __restrict__ flags,
                             int* __restrict__ cnt)
{
  int e = blockIdx.x * 256 + threadIdx.x;
  if (e >= N_NODES*KK) return;
  int i = e / KK;
  int d = knn[e];
  int mut = 0;
#pragma unroll
  for (int t = 0; t < KK; t++) mut |= (knn[d*KK + t] == i);
  flags[e] = mut;
  if (!mut) atomicAdd(&cnt[d], 1);
}

__global__ __launch_bounds__(1024) void scan_kernel(const int* __restrict__ cnt,
                                                    int* __restrict__ off)
{
  __shared__ int ssum[1024];
  int tid = threadIdx.x;
  int i0 = tid * 32;
  int loc[32];
  int s = 0;
#pragma unroll
  for (int j = 0; j < 32; j++) { loc[j] = s; s += cnt[i0 + j]; }
  ssum[tid] = s;
  __syncthreads();
  for (int d = 1; d < 1024; d <<= 1) {
    int t = (tid >= d) ? ssum[tid - d] : 0;
    __syncthreads();
    ssum[tid] += t;
    __syncthreads();
  }
  int bse = ssum[tid] - s;             // exclusive base
#pragma unroll
  for (int j = 0; j < 32; j++) off[i0 + j] = bse + loc[j];
  if (tid == 1023) off[N_NODES] = bse + s;
}

__global__ void fill_kernel(const int* __restrict__ knn, const int* __restrict__ flags,
                            const int* __restrict__ off, int* __restrict__ cursor,
                            int* __restrict__ extra)
{
  int e = blockIdx.x * 256 + threadIdx.x;
  if (e >= N_NODES*KK) return;
  if (flags[e]) return;
  int i = e / KK;
  int d = knn[e];
  int p = atomicAdd(&cursor[d], 1);
  extra[off[d] + p] = i;
}

// Y = X @ W (+ bias [*deg]) [+relu]; X:[n,128] f32, W:[128,128] row-major.
// OBF16: store Y as bf16 (RNE). Full W staged in LDS; ONE barrier.
// XCD-graph swizzle kept (neutral, harmless): p%8 in {2g,2g+1}.
template<int RELU, int DEG, int OBF16>
__global__ __launch_bounds__(256) void gemm128(const float* __restrict__ X,
    const float* __restrict__ W, const float* __restrict__ bias,
    const int* __restrict__ offs, void* __restrict__ Yv)
{
  __shared__ float ws[128*128];
  const int tid = threadIdx.x;
  const int p   = blockIdx.x;             // 512 blocks
  const int g   = (p & 7) >> 1;
  const int j   = ((p >> 3) << 1) | (p & 1);
  const int r0  = g*NPER + j*64;

  {
    const float4* W4 = (const float4*)W;
    float4* ws4 = (float4*)ws;
#pragma unroll
    for (int li = 0; li < 16; li++) ws4[tid + li*256] = W4[tid + li*256];
  }
  __syncthreads();

  const int tr = tid >> 4, tc = tid & 15;
  const int rr0 = tr*4, cc0 = tc*8;
  float acc[4][8];
#pragma unroll
  for (int a = 0; a < 4; a++)
#pragma unroll
    for (int c = 0; c < 8; c++) acc[a][c] = 0.f;

  for (int kc = 0; kc < 32; kc++) {
    float4 xr[4];
#pragma unroll
    for (int rr = 0; rr < 4; rr++)
      xr[rr] = *(const float4*)&X[(size_t)(r0 + rr0 + rr)*128 + kc*4];
#pragma unroll
    for (int kk = 0; kk < 4; kk++) {
      float4 wA = *(const float4*)&ws[(kc*4 + kk)*128 + cc0];
      float4 wB = *(const float4*)&ws[(kc*4 + kk)*128 + cc0 + 4];
      float wv[8] = {wA.x, wA.y, wA.z, wA.w, wB.x, wB.y, wB.z, wB.w};
      float xa[4] = {kk==0?xr[0].x:kk==1?xr[0].y:kk==2?xr[0].z:xr[0].w,
                     kk==0?xr[1].x:kk==1?xr[1].y:kk==2?xr[1].z:xr[1].w,
                     kk==0?xr[2].x:kk==1?xr[2].y:kk==2?xr[2].z:xr[2].w,
                     kk==0?xr[3].x:kk==1?xr[3].y:kk==2?xr[3].z:xr[3].w};
#pragma unroll
      for (int rr = 0; rr < 4; rr++)
#pragma unroll
        for (int cc = 0; cc < 8; cc++) acc[rr][cc] += xa[rr] * wv[cc];
    }
  }
#pragma unroll
  for (int rr = 0; rr < 4; rr++) {
    int r = r0 + rr0 + rr;
    float dg = 1.f;
    if (DEG) dg = (float)(KK + offs[r+1] - offs[r]);
    float o[8];
#pragma unroll
    for (int cc = 0; cc < 8; cc++) {
      float vv = acc[rr][cc] + bias[cc0+cc] * dg;
      if (RELU) vv = fmaxf(vv, 0.f);
      o[cc] = vv;
    }
    if (OBF16) {
      ushort* Y = (ushort*)Yv;
      unsigned pk[4];
#pragma unroll
      for (int q = 0; q < 4; q++)
        pk[q] = (unsigned)f2bf(o[2*q]) | ((unsigned)f2bf(o[2*q+1]) << 16);
      *(uint4*)&Y[(size_t)r*128 + cc0] = make_uint4(pk[0], pk[1], pk[2], pk[3]);
    } else {
      float* Y = (float*)Yv;
      *(float4*)&Y[(size_t)r*128 + cc0]     = make_float4(o[0], o[1], o[2], o[3]);
      *(float4*)&Y[(size_t)r*128 + cc0 + 4] = make_float4(o[4], o[5], o[6], o[7]);
    }
  }
}

// agg[d] = sum over in-neighbors s of relu(H[s] + (pos[d]-pos[s]) @ Wr).
// H bf16 [N,128] (256B rows): FOUR nodes per wave (16 lanes each, 8 cols/lane).
// [Round-26 version; r27's explicit MLP batching measured neutral -- hipcc
//  already extracts the available memory-level parallelism here.]
__global__ __launch_bounds__(256) void agg_kernel(const ushort* __restrict__ H,
    const float4* __restrict__ pos4, const int* __restrict__ knn,
    const int* __restrict__ off, const int* __restrict__ extra,
    const float* __restrict__ Wr, float* __restrict__ agg)
{
  const int lane = threadIdx.x & 63;
  const int w    = threadIdx.x >> 6;
  const int grp  = lane >> 4;             // node within wave
  const int hl   = lane & 15;             // lane within node group
  const int dblk = blockIdx.x;            // 2048 blocks
  const int g    = (dblk >> 1) & 3;
  const int nb   = ((dblk >> 3) << 1) | (dblk & 1);   // 0..511
  const int d    = g*NPER + nb*16 + w*4 + grp;
  const int c0   = hl * 8;

  // preload all 20 neighbor indices (80B contiguous)
  const int4* kn4 = (const int4*)&knn[d*KK];
  int4 i0 = kn4[0], i1 = kn4[1], i2 = kn4[2], i3 = kn4[3], i4 = kn4[4];
  const int e0 = off[d], e1 = off[d+1];
  const int idx[KK] = {i0.x,i0.y,i0.z,i0.w, i1.x,i1.y,i1.z,i1.w,
                       i2.x,i2.y,i2.z,i2.w, i3.x,i3.y,i3.z,i3.w,
                       i4.x,i4.y,i4.z,i4.w};

  // 8 columns of Wr per lane
  float w0[8], w1[8], w2[8];
#pragma unroll
  for (int jj = 0; jj < 8; jj++) {
    w0[jj] = Wr[0*DH + c0 + jj];
    w1[jj] = Wr[1*DH + c0 + jj];
    w2[jj] = Wr[2*DH + c0 + jj];
  }
  const float4 pd = pos4[d];
  const float px = pd.x, py = pd.y, pz = pd.z;

  float a[8];
#pragma unroll
  for (int jj = 0; jj < 8; jj++) a[jj] = 0.f;

#pragma unroll
  for (int t = 0; t < KK; t++) {
    int s = idx[t];
    float4 ps = pos4[s];
    float rx = px - ps.x, ry = py - ps.y, rz = pz - ps.z;
    uint4 hv = *(const uint4*)&H[(size_t)s*DH + c0];
    float h[8] = {bflo(hv.x), bfhi(hv.x), bflo(hv.y), bfhi(hv.y),
                  bflo(hv.z), bfhi(hv.z), bflo(hv.w), bfhi(hv.w)};
#pragma unroll
    for (int jj = 0; jj < 8; jj++) {
      float m = h[jj] + rx*w0[jj] + ry*w1[jj] + rz*w2[jj];
      a[jj] += fmaxf(m, 0.f);
    }
  }
  for (int t = e0; t < e1; t++) {
    int s = extra[t];
    float4 ps = pos4[s];
    float rx = px - ps.x, ry = py - ps.y, rz = pz - ps.z;
    uint4 hv = *(const uint4*)&H[(size_t)s*DH + c0];
    float h[8] = {bflo(hv.x), bfhi(hv.x), bflo(hv.y), bfhi(hv.y),
                  bflo(hv.z), bfhi(hv.z), bflo(hv.w), bfhi(hv.w)};
#pragma unroll
    for (int jj = 0; jj < 8; jj++) {
      float m = h[jj] + rx*w0[jj] + ry*w1[jj] + rz*w2[jj];
      a[jj] += fmaxf(m, 0.f);
    }
  }
  *(float4*)&agg[(size_t)d*DH + c0]     = make_float4(a[0], a[1], a[2], a[3]);
  *(float4*)&agg[(size_t)d*DH + c0 + 4] = make_float4(a[4], a[5], a[6], a[7]);
}

// logits[n] = dot(X[n], Wf) + bf — WIDE (128 blocks, coalesced streaming).
__global__ __launch_bounds__(256) void logits_kernel(const float* __restrict__ X,
    const float* __restrict__ Wf, const float* __restrict__ bf,
    float* __restrict__ logits)
{
  const int n = blockIdx.x * 256 + threadIdx.x;
  const float4* xr = (const float4*)&X[(size_t)n*128];
  float acc = 0.f;
#pragma unroll 8
  for (int q = 0; q < 32; q++) {
    float4 xv = xr[q];
    float4 wv = *(const float4*)&Wf[q*4];
    acc += xv.x*wv.x + xv.y*wv.y + xv.z*wv.z + xv.w*wv.w;
  }
  logits[n] = acc + bf[0];
}

// per-graph softmax over 8192 logits (128 KB total; registers + 2 block reduces).
__global__ __launch_bounds__(1024) void softmax_kernel(const float* __restrict__ logits,
    float* __restrict__ out)
{
  __shared__ float red[16];
  __shared__ float bcast;
  const int g = blockIdx.x, tid = threadIdx.x;
  const int lane = tid & 63, wid = tid >> 6;
  float lg[8];
#pragma unroll
  for (int k = 0; k < 8; k++) lg[k] = logits[g*NPER + k*1024 + tid];
  float m = lg[0];
#pragma unroll
  for (int k = 1; k < 8; k++) m = fmaxf(m, lg[k]);
  for (int o = 1; o < 64; o <<= 1) m = fmaxf(m, __shfl_xor(m, o, 64));
  if (lane == 0) red[wid] = m;
  __syncthreads();
  if (tid == 0) {
    float mm = red[0];
    for (int i = 1; i < 16; i++) mm = fmaxf(mm, red[i]);
    bcast = mm;
  }
  __syncthreads();
  const float M = bcast;
  float e[8];
  float s = 0.f;
#pragma unroll
  for (int k = 0; k < 8; k++) { e[k] = expf(lg[k] - M); s += e[k]; }
  for (int o = 1; o < 64; o <<= 1) s += __shfl_xor(s, o, 64);
  __syncthreads();
  if (lane == 0) red[wid] = s;
  __syncthreads();
  if (tid == 0) {
    float ss = 0.f;
    for (int i = 0; i < 16; i++) ss += red[i];
    bcast = ss;
  }
  __syncthreads();
  const float S = bcast;
#pragma unroll
  for (int k = 0; k < 8; k++) {
    int n = g*NPER + k*1024 + tid;
    out[n] = e[k] / S;
  }
}

extern "C" void kernel_launch(void* const* d_in, const int* in_sizes, int n_in,
                              void* d_out, int out_size, void* d_ws, size_t ws_size,
                              hipStream_t stream)
{
  const float* x   = (const float*)d_in[0];
  const float* pos = (const float*)d_in[1];
  // d_in[2] = batch (unused: sorted, equal-size graphs)
  const float* W1s = (const float*)d_in[3];
  const float* b1s = (const float*)d_in[4];
  const float* W2s = (const float*)d_in[5];
  const float* b2s = (const float*)d_in[6];
  const float* Wf  = (const float*)d_in[7];
  const float* bf  = (const float*)d_in[8];
  float* out = (float*)d_out;

  char* wsb = (char*)d_ws;
  size_t o = 0;
  auto alloc = [&](size_t bytes) { void* p = wsb + o; o += (bytes + 255) & ~255ull; return p; };
  int*    knn    = (int*)   alloc((size_t)N_NODES*KK*4);
  int*    flags  = (int*)   alloc((size_t)N_NODES*KK*4);
  int*    cnt    = (int*)   alloc((size_t)(N_NODES+1)*4);
  int*    off    = (int*)   alloc((size_t)(N_NODES+1)*4);
  int*    cursor = (int*)   alloc((size_t)N_NODES*4);
  int*    extra  = (int*)   alloc((size_t)N_NODES*KK*4);
  ushort* H      = (ushort*)alloc((size_t)N_NODES*DH*2);   // bf16
  float*  agg    = (float*) alloc((size_t)N_NODES*DH*4);
  float*  xbuf   = (float*) alloc((size_t)N_NODES*DH*4);
  float4* pos4   = (float4*)alloc((size_t)N_NODES*16);
  float*  logits = (float*) alloc((size_t)N_NODES*4);
  (void)ws_size; (void)in_sizes; (void)n_in; (void)out_size;

  hipMemsetAsync(cnt,    0, (size_t)(N_NODES+1)*4, stream);
  hipMemsetAsync(cursor, 0, (size_t)N_NODES*4,     stream);

  knn_kernel <<<N_NODES/8, 256, 0, stream>>>(pos, knn);
  pos4_kernel<<<N_NODES/256, 256, 0, stream>>>(pos, pos4);
  count_kernel<<<(N_NODES*KK + 255)/256, 256, 0, stream>>>(knn, flags, cnt);
  scan_kernel<<<1, 1024, 0, stream>>>(cnt, off);
  fill_kernel<<<(N_NODES*KK + 255)/256, 256, 0, stream>>>(knn, flags, off, cursor, extra);

  const float* xin = x;
  for (int l = 0; l < 3; l++) {
    const float* W1 = W1s + (size_t)l*131*128;   // rows 0..127: x-part
    const float* Wr = W1 + 128*128;              // rows 128..130: rel-part
    const float* b1 = b1s + l*128;
    const float* W2 = W2s + (size_t)l*128*128;
    const float* b2 = b2s + l*128;
    gemm128<0,0,1><<<N_NODES/64, 256, 0, stream>>>(xin, W1, b1, nullptr, H);
    agg_kernel  <<<N_NODES/16, 256, 0, stream>>>(H, pos4, knn, off, extra, Wr, agg);
    gemm128<1,1,0><<<N_NODES/64, 256, 0, stream>>>(agg, W2, b2, off, xbuf);
    xin = xbuf;
  }
  logits_kernel <<<N_NODES/256, 256, 0, stream>>>(xbuf, Wf, bf, logits);
  softmax_kernel<<<NB, 1024, 0, stream>>>(logits, out);
}